// Round 1
// baseline (405.744 us; speedup 1.0000x reference)
//
#include <hip/hip_runtime.h>
#include <math.h>

#define N_PTS 50000
#define CCH   64
#define KP    15
#define NH    32
#define SIGMA 0.7f
#define BN_EPS 1e-5f
#define LEAKY 0.1f
#define QB    16

// ---------------- K1: h = s_feats @ W1, accumulate BN sum/sumsq ----------------
__global__ __launch_bounds__(256) void k_bn_stats(const float* __restrict__ s_feats,
                                                  const float* __restrict__ W1,
                                                  float* __restrict__ bn) {
    int t  = threadIdx.x;
    int c  = t & 63;
    int ml = t >> 6;  // 0..3 row slot
    float acc_s = 0.f, acc_q = 0.f;
    int stride = gridDim.x * 4;
    for (int m = blockIdx.x * 4 + ml; m < N_PTS; m += stride) {
        const float* row = s_feats + m * CCH;
        float h = 0.f;
        #pragma unroll
        for (int i = 0; i < CCH; ++i) h += row[i] * W1[i * CCH + c];
        acc_s += h;
        acc_q += h * h;
    }
    __shared__ float red[2][256];
    red[0][t] = acc_s;
    red[1][t] = acc_q;
    __syncthreads();
    if (t < 64) {
        float s = red[0][t] + red[0][64 + t] + red[0][128 + t] + red[0][192 + t];
        float q = red[1][t] + red[1][64 + t] + red[1][128 + t] + red[1][192 + t];
        atomicAdd(&bn[t], s);
        atomicAdd(&bn[64 + t], q);
    }
}

// ---------------- K2: fold BN into per-channel a*h + b ----------------
__global__ void k_bn_final(const float* __restrict__ bn,
                           const float* __restrict__ gamma,
                           const float* __restrict__ beta,
                           float* __restrict__ ab) {
    int c = threadIdx.x;
    if (c < 64) {
        float mu  = bn[c] * (1.0f / N_PTS);
        float var = bn[64 + c] * (1.0f / N_PTS) - mu * mu;
        float a   = gamma[c] * rsqrtf(var + BN_EPS);
        ab[c]      = a;
        ab[64 + c] = beta[c] - mu * a;
    }
}

// ---------------- K3: fused main kernel, QB queries per block ----------------
__global__ __launch_bounds__(256) void k_main(
    const float* __restrict__ q_pts, const float* __restrict__ s_pts,
    const float* __restrict__ s_feats, const int* __restrict__ nb,
    const float* __restrict__ kpts, const float* __restrict__ W1,
    const float* __restrict__ W2, const float* __restrict__ b2,
    const float* __restrict__ ab, float* __restrict__ out) {

    __shared__ float G[QB][CCH];          // activated MLP-hidden rows   (4 KB)
    __shared__ float S[QB][KP][CCH];      // per-(q,k) weighted feat sums (61.4 KB)
    __shared__ float kp[KP][3];
    __shared__ int   nK[QB * NH];
    __shared__ float nI[QB * NH];
    __shared__ int   nId[QB * NH];
    __shared__ int   activeK[QB];

    int t  = threadIdx.x;
    int m0 = blockIdx.x * QB;

    // ---- init: stage kernel points, zero S and activeK ----
    if (t < KP * 3) ((float*)kp)[t] = kpts[t];
    if (t < QB) activeK[t] = 0;
    {
        float* sp = &S[0][0][0];
        for (int i = t; i < QB * KP * CCH; i += 256) sp[i] = 0.f;
    }

    // ---- phase 0: G = leaky(a * (s_feats@W1) + b) for QB rows ----
    {
        int c  = t & 63;
        int ql = t >> 6;  // 0..3
        float a = ab[c], bsh = ab[64 + c];
        #pragma unroll
        for (int j = 0; j < 4; ++j) {
            int q = ql + j * 4;
            const float* row = s_feats + (m0 + q) * CCH;
            float h = 0.f;
            #pragma unroll
            for (int i = 0; i < CCH; ++i) h += row[i] * W1[i * CCH + c];
            h = a * h + bsh;
            G[q][c] = (h > 0.f) ? h : LEAKY * h;
        }
    }
    __syncthreads();

    // ---- phase 1: per-neighbor nearest kernel point + influence ----
    for (int task = t; task < QB * NH; task += 256) {
        int q  = task >> 5;
        int hh = task & 31;
        int m  = m0 + q;
        int idx = nb[m * NH + hh];
        int kbest = -1;
        float infl = 0.f;
        if (idx >= 0 && idx < N_PTS) {
            float px = s_pts[idx * 3 + 0] - q_pts[m * 3 + 0];
            float py = s_pts[idx * 3 + 1] - q_pts[m * 3 + 1];
            float pz = s_pts[idx * 3 + 2] - q_pts[m * 3 + 2];
            float best = 1e30f; int bi = 0;
            #pragma unroll
            for (int k = 0; k < KP; ++k) {
                float dx = px - kp[k][0], dy = py - kp[k][1], dz = pz - kp[k][2];
                float d = dx * dx + dy * dy + dz * dz;
                if (d < best) { best = d; bi = k; }
            }
            infl = 1.f - sqrtf(best) * (1.0f / SIGMA);
            if (infl > 0.f) { kbest = bi; atomicOr(&activeK[q], 1 << bi); }
            else infl = 0.f;
        }
        nK[task]  = kbest;
        nI[task]  = infl;
        nId[task] = idx;
    }
    __syncthreads();

    // ---- phase 2: S[q][k][c] += infl * feats[idx][c]  (thread = (q, 4-chan group)) ----
    {
        int q  = t >> 4;   // 0..15
        int cg = t & 15;   // c = cg*4 .. cg*4+3
        const float4* feats4 = (const float4*)s_feats;
        for (int hh = 0; hh < NH; ++hh) {
            int k = nK[q * NH + hh];
            if (k < 0) continue;
            float infl = nI[q * NH + hh];
            int   idx  = nId[q * NH + hh];
            float4 f = feats4[idx * 16 + cg];
            float4* sp = (float4*)&S[q][k][cg * 4];
            float4 v = *sp;
            v.x += infl * f.x; v.y += infl * f.y;
            v.z += infl * f.z; v.w += infl * f.w;
            *sp = v;
        }
    }
    __syncthreads();

    // ---- phase 3: out[q,c] = sum_k (G[q]·W2[:,k*64+c] + b2) * S[q][k][c] ----
    {
        int c  = t & 63;
        int qg = t >> 6;          // wave-uniform: each wave owns 4 queries
        int q0 = qg * 4;
        int amask = activeK[q0] | activeK[q0 + 1] | activeK[q0 + 2] | activeK[q0 + 3];
        float acc0 = 0.f, acc1 = 0.f, acc2 = 0.f, acc3 = 0.f;
        const float4* G0 = (const float4*)&G[q0 + 0][0];
        const float4* G1 = (const float4*)&G[q0 + 1][0];
        const float4* G2 = (const float4*)&G[q0 + 2][0];
        const float4* G3 = (const float4*)&G[q0 + 3][0];
        for (int k = 0; k < KP; ++k) {
            if (!((amask >> k) & 1)) continue;
            const float* w2col = W2 + k * 64 + c;  // stride 960 over i
            float bb = b2[k * 64 + c];
            float cw0 = bb, cw1 = bb, cw2 = bb, cw3 = bb;
            #pragma unroll
            for (int i4 = 0; i4 < 16; ++i4) {
                float wa = w2col[(i4 * 4 + 0) * 960];
                float wb = w2col[(i4 * 4 + 1) * 960];
                float wc = w2col[(i4 * 4 + 2) * 960];
                float wd = w2col[(i4 * 4 + 3) * 960];
                float4 g0 = G0[i4], g1 = G1[i4], g2 = G2[i4], g3 = G3[i4];
                cw0 += g0.x * wa + g0.y * wb + g0.z * wc + g0.w * wd;
                cw1 += g1.x * wa + g1.y * wb + g1.z * wc + g1.w * wd;
                cw2 += g2.x * wa + g2.y * wb + g2.z * wc + g2.w * wd;
                cw3 += g3.x * wa + g3.y * wb + g3.z * wc + g3.w * wd;
            }
            acc0 += cw0 * S[q0 + 0][k][c];
            acc1 += cw1 * S[q0 + 1][k][c];
            acc2 += cw2 * S[q0 + 2][k][c];
            acc3 += cw3 * S[q0 + 3][k][c];
        }
        out[(m0 + q0 + 0) * CCH + c] = acc0;
        out[(m0 + q0 + 1) * CCH + c] = acc1;
        out[(m0 + q0 + 2) * CCH + c] = acc2;
        out[(m0 + q0 + 3) * CCH + c] = acc3;
    }
}

extern "C" void kernel_launch(void* const* d_in, const int* in_sizes, int n_in,
                              void* d_out, int out_size, void* d_ws, size_t ws_size,
                              hipStream_t stream) {
    const float* q_pts   = (const float*)d_in[0];
    const float* s_pts   = (const float*)d_in[1];
    const float* s_feats = (const float*)d_in[2];
    const int*   nb      = (const int*)d_in[3];
    const float* kpts    = (const float*)d_in[4];
    const float* W1      = (const float*)d_in[5];
    const float* gamma   = (const float*)d_in[6];
    const float* beta    = (const float*)d_in[7];
    const float* W2      = (const float*)d_in[8];
    const float* b2      = (const float*)d_in[9];
    float* out = (float*)d_out;
    float* ws  = (float*)d_ws;   // [0:64] sum, [64:128] sumsq, [128:192] a, [192:256] b

    hipMemsetAsync(ws, 0, 128 * sizeof(float), stream);
    k_bn_stats<<<512, 256, 0, stream>>>(s_feats, W1, ws);
    k_bn_final<<<1, 64, 0, stream>>>(ws, gamma, beta, ws + 128);
    k_main<<<N_PTS / QB, 256, 0, stream>>>(q_pts, s_pts, s_feats, nb, kpts,
                                           W1, W2, b2, ws + 128, out);
}

// Round 2
// 186.243 us; speedup vs baseline: 2.1786x; 2.1786x over previous
//
#include <hip/hip_runtime.h>
#include <math.h>

#define N_PTS 50000
#define CCH   64
#define KP    15
#define NH    32
#define SIGMA 0.7f
#define BN_EPS 1e-5f
#define LEAKY 0.1f
#define QB    16
#define NTILES 60          // 960 / 16
#define CWS   18           // cwT row stride in bf16 elems (16 q + 2 pad -> 2-way banks, free)

typedef short bf16x8 __attribute__((ext_vector_type(8)));
typedef float floatx4 __attribute__((ext_vector_type(4)));

__device__ __forceinline__ unsigned short f2b(float f) {
    union { float f; unsigned u; } v; v.f = f;
    return (unsigned short)((v.u + 0x7FFFu + ((v.u >> 16) & 1u)) >> 16);  // RNE
}
__device__ __forceinline__ float b2f(unsigned short b) {
    union { unsigned u; float f; } v; v.u = ((unsigned)b) << 16;
    return v.f;
}

// ---------- K0: repack W2 (fp32, [64][960]) into bf16 B-fragment order ----------
// layout: w2b[((tile*2 + kstep)*64 + lane)*8 + j] = bf16(W2[k][n]),
//   k = kstep*32 + (lane>>4)*8 + j,  n = tile*16 + (lane&15)
__global__ void k_w2prep(const float* __restrict__ W2, unsigned short* __restrict__ w2b) {
    int g = blockIdx.x * 256 + threadIdx.x;      // 60*2*64 = 7680 exactly
    int lane = g & 63, s = (g >> 6) & 1, tt = g >> 7;
    int col = lane & 15, quad = lane >> 4;
    ushort4 lo, hi;
    int base = (s * 32 + quad * 8) * 960 + tt * 16 + col;
    lo.x = f2b(W2[base + 0 * 960]); lo.y = f2b(W2[base + 1 * 960]);
    lo.z = f2b(W2[base + 2 * 960]); lo.w = f2b(W2[base + 3 * 960]);
    hi.x = f2b(W2[base + 4 * 960]); hi.y = f2b(W2[base + 5 * 960]);
    hi.z = f2b(W2[base + 6 * 960]); hi.w = f2b(W2[base + 7 * 960]);
    *(ushort4*)(w2b + g * 8)     = lo;
    *(ushort4*)(w2b + g * 8 + 4) = hi;
}

// ---------- K1: BN sum/sumsq of h = s_feats @ W1 (W1 column held in VGPRs) ----------
__global__ __launch_bounds__(256) void k_bn_stats(const float* __restrict__ sf,
                                                  const float* __restrict__ W1,
                                                  float* __restrict__ bn) {
    int t = threadIdx.x;
    int c = t & 63, ml = t >> 6;
    float w1c[64];
    #pragma unroll
    for (int i = 0; i < 64; ++i) w1c[i] = W1[i * 64 + c];
    __shared__ float rows[4][64];
    float acc_s = 0.f, acc_q = 0.f;
    int stride = gridDim.x * 4;
    for (int m0 = blockIdx.x * 4; m0 < N_PTS; m0 += stride) {   // 50000 % 4 == 0
        __syncthreads();
        ((float*)rows)[t] = sf[m0 * 64 + t];
        __syncthreads();
        float h = 0.f;
        #pragma unroll
        for (int i4 = 0; i4 < 16; ++i4) {
            float4 r = *(const float4*)&rows[ml][i4 * 4];
            h += r.x * w1c[i4 * 4] + r.y * w1c[i4 * 4 + 1]
               + r.z * w1c[i4 * 4 + 2] + r.w * w1c[i4 * 4 + 3];
        }
        acc_s += h;
        acc_q += h * h;
    }
    __shared__ float red[2][256];
    red[0][t] = acc_s; red[1][t] = acc_q;
    __syncthreads();
    if (t < 64) {
        float s = red[0][t] + red[0][64 + t] + red[0][128 + t] + red[0][192 + t];
        float q = red[1][t] + red[1][64 + t] + red[1][128 + t] + red[1][192 + t];
        atomicAdd(&bn[t], s);
        atomicAdd(&bn[64 + t], q);
    }
}

// ---------- K2: fold BN into per-channel a*h + b ----------
__global__ void k_bn_final(const float* __restrict__ bn,
                           const float* __restrict__ gamma,
                           const float* __restrict__ beta,
                           float* __restrict__ ab) {
    int c = threadIdx.x;
    if (c < 64) {
        float mu  = bn[c] * (1.0f / N_PTS);
        float var = bn[64 + c] * (1.0f / N_PTS) - mu * mu;
        float a   = gamma[c] * rsqrtf(var + BN_EPS);
        ab[c]      = a;
        ab[64 + c] = beta[c] - mu * a;
    }
}

// ---------- K3: fused main kernel ----------
__global__ __launch_bounds__(256, 3) void k_main(
    const float* __restrict__ q_pts, const float* __restrict__ s_pts,
    const float* __restrict__ s_feats, const int* __restrict__ nb,
    const float* __restrict__ kpts, const float* __restrict__ W1,
    const float* __restrict__ b2, const unsigned short* __restrict__ w2b,
    const float* __restrict__ ab, float* __restrict__ out) {

    __shared__ __align__(16) unsigned short Afrag[2][64][8];   // 2 KB, A-frag order
    __shared__ __align__(16) unsigned short cwT[960 * CWS];    // 34.5 KB, cw[n][q] bf16
    __shared__ float rows16[QB][64];                           // 4 KB
    __shared__ float kp[KP * 3];
    __shared__ int   nCnt[QB];
    __shared__ int   nIdxL[QB][NH];
    __shared__ float nInfL[QB][NH];
    __shared__ int   nKL[QB][NH];

    int t = threadIdx.x;
    int m0 = blockIdx.x * QB;
    int lane = t & 63;
    int wv = t >> 6;

    if (t < KP * 3) kp[t] = kpts[t];
    if (t >= 240) nCnt[t - 240] = 0;
    {   // stage the 16 query feature rows (coalesced float4)
        int q = t >> 4, i4 = t & 15;
        *(float4*)&rows16[q][i4 * 4] = *(const float4*)&s_feats[(m0 + q) * 64 + i4 * 4];
    }
    __syncthreads();

    // ---- phase 0: h = rows16 @ W1, BN fold + leaky, emit bf16 A-fragments ----
    {
        int c = lane;
        float w1c[64];
        #pragma unroll
        for (int i = 0; i < 64; ++i) w1c[i] = W1[i * 64 + c];
        float a = ab[c], bs = ab[64 + c];
        int s = c >> 5, quad = (c >> 3) & 3, j = c & 7;
        #pragma unroll
        for (int jj = 0; jj < 4; ++jj) {
            int q = wv * 4 + jj;
            float h = 0.f;
            #pragma unroll
            for (int i4 = 0; i4 < 16; ++i4) {
                float4 r = *(const float4*)&rows16[q][i4 * 4];
                h += r.x * w1c[i4 * 4] + r.y * w1c[i4 * 4 + 1]
                   + r.z * w1c[i4 * 4 + 2] + r.w * w1c[i4 * 4 + 3];
            }
            h = a * h + bs;
            h = h > 0.f ? h : LEAKY * h;
            Afrag[s][quad * 16 + q][j] = f2b(h);
        }
    }
    __syncthreads();

    // ---- phase A: cw tile via MFMA; each wave owns 15 n-tiles ----
    {
        bf16x8 a0 = *(const bf16x8*)&Afrag[0][lane][0];   // ds_read_b128, conflict-free
        bf16x8 a1 = *(const bf16x8*)&Afrag[1][lane][0];
        int col = lane & 15, quad = lane >> 4;
        for (int ti = 0; ti < 15; ++ti) {
            int tt = wv * 15 + ti;
            bf16x8 bf0 = *(const bf16x8*)(w2b + ((tt * 2 + 0) * 64 + lane) * 8);
            bf16x8 bf1 = *(const bf16x8*)(w2b + ((tt * 2 + 1) * 64 + lane) * 8);
            floatx4 acc = {0.f, 0.f, 0.f, 0.f};
            acc = __builtin_amdgcn_mfma_f32_16x16x32_bf16(a0, bf0, acc, 0, 0, 0);
            acc = __builtin_amdgcn_mfma_f32_16x16x32_bf16(a1, bf1, acc, 0, 0, 0);
            int n = tt * 16 + col;
            float bb = b2[n];
            // D layout: row(m) = quad*4+reg, col(n) = lane&15 -> cwT[n][m]
            unsigned short* dst = &cwT[n * CWS + quad * 4];
            ushort2 w01, w23;
            w01.x = f2b(acc[0] + bb); w01.y = f2b(acc[1] + bb);
            w23.x = f2b(acc[2] + bb); w23.y = f2b(acc[3] + bb);
            *(ushort2*)(dst)     = w01;
            *(ushort2*)(dst + 2) = w23;
        }
    }

    // ---- phase 1: neighbor 1-NN kernel point + influence, compact active list ----
    for (int task = t; task < QB * NH; task += 256) {
        int q = task >> 5, hh = task & 31;
        int m = m0 + q;
        int idx = nb[m * NH + hh];
        float px = s_pts[idx * 3 + 0] - q_pts[m * 3 + 0];
        float py = s_pts[idx * 3 + 1] - q_pts[m * 3 + 1];
        float pz = s_pts[idx * 3 + 2] - q_pts[m * 3 + 2];
        float best = 1e30f; int bi = 0;
        #pragma unroll
        for (int k = 0; k < KP; ++k) {
            float dx = px - kp[k * 3], dy = py - kp[k * 3 + 1], dz = pz - kp[k * 3 + 2];
            float d = dx * dx + dy * dy + dz * dz;
            if (d < best) { best = d; bi = k; }
        }
        float infl = 1.f - sqrtf(best) * (1.0f / SIGMA);
        if (infl > 0.f) {
            int pos = atomicAdd(&nCnt[q], 1);
            nIdxL[q][pos] = idx;
            nInfL[q][pos] = infl;
            nKL[q][pos]   = bi;
        }
    }
    __syncthreads();

    // ---- phase B: out[q,c] = sum_j infl * feat[idx,c] * cw[q, k_j, c] ----
    {
        int c = lane;   // wave handles 4 queries; idx/infl/k wave-uniform per step
        #pragma unroll
        for (int qi = 0; qi < 4; ++qi) {
            int q = wv * 4 + qi;
            int na = nCnt[q];
            float acc = 0.f;
            for (int jj = 0; jj < na; ++jj) {
                int   idx  = nIdxL[q][jj];
                float infl = nInfL[q][jj];
                int   k    = nKL[q][jj];
                float f = s_feats[idx * 64 + c];                  // coalesced 256B row
                float w = b2f(cwT[(k * 64 + c) * CWS + q]);       // 2-way banks, free
                acc += infl * f * w;
            }
            out[(m0 + q) * 64 + c] = acc;
        }
    }
}

extern "C" void kernel_launch(void* const* d_in, const int* in_sizes, int n_in,
                              void* d_out, int out_size, void* d_ws, size_t ws_size,
                              hipStream_t stream) {
    const float* q_pts   = (const float*)d_in[0];
    const float* s_pts   = (const float*)d_in[1];
    const float* s_feats = (const float*)d_in[2];
    const int*   nb      = (const int*)d_in[3];
    const float* kpts    = (const float*)d_in[4];
    const float* W1      = (const float*)d_in[5];
    const float* gamma   = (const float*)d_in[6];
    const float* beta    = (const float*)d_in[7];
    const float* W2      = (const float*)d_in[8];
    const float* b2      = (const float*)d_in[9];
    float* out = (float*)d_out;

    float* ws = (float*)d_ws;
    float* bn = ws;                                        // 128 fp32
    float* ab = ws + 128;                                  // 128 fp32
    unsigned short* w2b = (unsigned short*)(ws + 256);     // 61440 bf16 = 123 KB

    hipMemsetAsync(bn, 0, 128 * sizeof(float), stream);
    k_w2prep<<<30, 256, 0, stream>>>(W2, w2b);
    k_bn_stats<<<1024, 256, 0, stream>>>(s_feats, W1, bn);
    k_bn_final<<<1, 64, 0, stream>>>(bn, gamma, beta, ab);
    k_main<<<N_PTS / QB, 256, 0, stream>>>(q_pts, s_pts, s_feats, nb, kpts,
                                           W1, b2, w2b, ab, out);
}

// Round 3
// 161.800 us; speedup vs baseline: 2.5077x; 1.1511x over previous
//
#include <hip/hip_runtime.h>
#include <math.h>

#define N_PTS 50000
#define CCH   64
#define KP    15
#define NH    32
#define SIGMA 0.7f
#define BN_EPS 1e-5f
#define LEAKY 0.1f
#define QB    16
#define CWS   18           // cwT row stride in bf16 (16 q + 2 pad -> 2-way banks, free)
#define STATS_BLOCKS 512

typedef short bf16x8 __attribute__((ext_vector_type(8)));
typedef float floatx4 __attribute__((ext_vector_type(4)));

__device__ __forceinline__ unsigned short f2b(float f) {
    union { float f; unsigned u; } v; v.f = f;
    return (unsigned short)((v.u + 0x7FFFu + ((v.u >> 16) & 1u)) >> 16);  // RNE
}
__device__ __forceinline__ float b2f(unsigned short b) {
    union { unsigned u; float f; } v; v.u = ((unsigned)b) << 16;
    return v.f;
}

// ---------- K1: blocks [0,512): h = sf@W1 -> hst (bf16) + BN sum/sumsq.
//             blocks [512,542): repack W2 into bf16 B-fragment order. ----------
__global__ __launch_bounds__(256) void k_prep(const float* __restrict__ sf,
                                              const float* __restrict__ W1,
                                              const float* __restrict__ W2,
                                              float* __restrict__ bn,
                                              unsigned short* __restrict__ hst,
                                              unsigned short* __restrict__ w2b) {
    int t = threadIdx.x;
    if (blockIdx.x >= STATS_BLOCKS) {
        // W2 repack: w2b[((tile*2+kstep)*64+lane)*8+j] = bf16(W2[k][n]),
        //   k = kstep*32 + (lane>>4)*8 + j, n = tile*16 + (lane&15)
        int g = (blockIdx.x - STATS_BLOCKS) * 256 + t;   // 7680 exactly
        int lane = g & 63, s = (g >> 6) & 1, tt = g >> 7;
        int col = lane & 15, quad = lane >> 4;
        int base = (s * 32 + quad * 8) * 960 + tt * 16 + col;
        ushort4 lo, hi;
        lo.x = f2b(W2[base + 0 * 960]); lo.y = f2b(W2[base + 1 * 960]);
        lo.z = f2b(W2[base + 2 * 960]); lo.w = f2b(W2[base + 3 * 960]);
        hi.x = f2b(W2[base + 4 * 960]); hi.y = f2b(W2[base + 5 * 960]);
        hi.z = f2b(W2[base + 6 * 960]); hi.w = f2b(W2[base + 7 * 960]);
        *(ushort4*)(w2b + g * 8)     = lo;
        *(ushort4*)(w2b + g * 8 + 4) = hi;
        return;
    }
    int c = t & 63, ml = t >> 6;
    float w1c[64];
    #pragma unroll
    for (int i = 0; i < 64; ++i) w1c[i] = W1[i * 64 + c];
    __shared__ float rows[4][64];
    float acc_s = 0.f, acc_q = 0.f;
    for (int m0 = blockIdx.x * 4; m0 < N_PTS; m0 += STATS_BLOCKS * 4) {
        __syncthreads();
        ((float*)rows)[t] = sf[m0 * 64 + t];
        __syncthreads();
        float h = 0.f;
        #pragma unroll
        for (int i4 = 0; i4 < 16; ++i4) {
            float4 r = *(const float4*)&rows[ml][i4 * 4];
            h += r.x * w1c[i4 * 4] + r.y * w1c[i4 * 4 + 1]
               + r.z * w1c[i4 * 4 + 2] + r.w * w1c[i4 * 4 + 3];
        }
        acc_s += h;
        acc_q += h * h;
        hst[(m0 + ml) * 64 + c] = f2b(h);      // 128B/wave coalesced
    }
    __shared__ float red[2][256];
    red[0][t] = acc_s; red[1][t] = acc_q;
    __syncthreads();
    if (t < 64) {
        float s = red[0][t] + red[0][64 + t] + red[0][128 + t] + red[0][192 + t];
        float q = red[1][t] + red[1][64 + t] + red[1][128 + t] + red[1][192 + t];
        atomicAdd(&bn[t], s);
        atomicAdd(&bn[64 + t], q);
    }
}

// ---------- K2: fused main kernel ----------
__global__ __launch_bounds__(256, 4) void k_main(
    const float* __restrict__ q_pts, const float* __restrict__ s_pts,
    const float* __restrict__ s_feats, const int* __restrict__ nb,
    const float* __restrict__ kpts, const float* __restrict__ gamma,
    const float* __restrict__ beta, const float* __restrict__ bn,
    const float* __restrict__ b2, const unsigned short* __restrict__ w2b,
    const unsigned short* __restrict__ hst, float* __restrict__ out) {

    __shared__ __align__(16) unsigned short cwT[960 * CWS];  // 34.56 KB: cw[n][q] bf16
    __shared__ float abS[128];                               // BN fold a[64], b[64]
    __shared__ float kp[48];
    __shared__ int   nCnt[QB];
    __shared__ int   nPack[QB][NH];                          // idx | (k<<20)
    __shared__ float nInf[QB][NH];

    int t = threadIdx.x;
    int lane = t & 63, wv = t >> 6;
    int m0 = blockIdx.x * QB;

    if (t < 64) {   // inline BN finalize (replaces the k_bn_final kernel)
        float mu  = bn[t] * (1.0f / N_PTS);
        float var = bn[64 + t] * (1.0f / N_PTS) - mu * mu;
        float a   = gamma[t] * rsqrtf(var + BN_EPS);
        abS[t]      = a;
        abS[64 + t] = beta[t] - mu * a;
    }
    if (t < KP * 3) kp[t] = kpts[t];
    if (t >= 240) nCnt[t - 240] = 0;
    __syncthreads();

    // ---- A-fragments directly in registers: fold BN + leaky on bf16 h rows ----
    int row = lane & 15, half = lane >> 4;
    bf16x8 a0, a1;
    {
        const unsigned short* hrow = hst + (m0 + row) * 64 + half * 8;
        bf16x8 r0 = *(const bf16x8*)(hrow);        // c = half*8 + j
        bf16x8 r1 = *(const bf16x8*)(hrow + 32);   // c = 32 + half*8 + j
        #pragma unroll
        for (int j = 0; j < 8; ++j) {
            int c0 = half * 8 + j;
            float g0 = abS[c0] * b2f((unsigned short)r0[j]) + abS[64 + c0];
            g0 = g0 > 0.f ? g0 : LEAKY * g0;
            a0[j] = (short)f2b(g0);
            int c1 = 32 + half * 8 + j;
            float g1 = abS[c1] * b2f((unsigned short)r1[j]) + abS[64 + c1];
            g1 = g1 > 0.f ? g1 : LEAKY * g1;
            a1[j] = (short)f2b(g1);
        }
    }

    // ---- phase A: cw = G @ W2 via MFMA; each wave owns 15 n-tiles ----
    {
        int col = lane & 15, quad = lane >> 4;
        for (int ti = 0; ti < 15; ++ti) {
            int tt = wv * 15 + ti;
            bf16x8 bf0 = *(const bf16x8*)(w2b + ((tt * 2 + 0) * 64 + lane) * 8);
            bf16x8 bf1 = *(const bf16x8*)(w2b + ((tt * 2 + 1) * 64 + lane) * 8);
            floatx4 acc = {0.f, 0.f, 0.f, 0.f};
            acc = __builtin_amdgcn_mfma_f32_16x16x32_bf16(a0, bf0, acc, 0, 0, 0);
            acc = __builtin_amdgcn_mfma_f32_16x16x32_bf16(a1, bf1, acc, 0, 0, 0);
            int n = tt * 16 + col;
            float bb = b2[n];
            unsigned short* dst = &cwT[n * CWS + quad * 4];   // D: row(q)=quad*4+reg
            ushort2 w01, w23;
            w01.x = f2b(acc[0] + bb); w01.y = f2b(acc[1] + bb);
            w23.x = f2b(acc[2] + bb); w23.y = f2b(acc[3] + bb);
            *(ushort2*)(dst)     = w01;
            *(ushort2*)(dst + 2) = w23;
        }
    }

    // ---- phase 1: neighbor 1-NN kernel point + influence, compacted ----
    for (int task = t; task < QB * NH; task += 256) {
        int q = task >> 5, hh = task & 31;
        int m = m0 + q;
        int idx = nb[m * NH + hh];
        float px = s_pts[idx * 3 + 0] - q_pts[m * 3 + 0];
        float py = s_pts[idx * 3 + 1] - q_pts[m * 3 + 1];
        float pz = s_pts[idx * 3 + 2] - q_pts[m * 3 + 2];
        float best = 1e30f; int bi = 0;
        #pragma unroll
        for (int k = 0; k < KP; ++k) {
            float dx = px - kp[k * 3], dy = py - kp[k * 3 + 1], dz = pz - kp[k * 3 + 2];
            float d = dx * dx + dy * dy + dz * dz;
            if (d < best) { best = d; bi = k; }
        }
        float infl = 1.f - sqrtf(best) * (1.0f / SIGMA);
        if (infl > 0.f) {
            int pos = atomicAdd(&nCnt[q], 1);
            nPack[q][pos] = idx | (bi << 20);
            nInf[q][pos]  = infl;
        }
    }
    __syncthreads();

    // ---- phase B: out[q,c] = sum_j infl * feat[idx,c] * cw[k_j*64+c][q] ----
    {
        int c = lane;
        #pragma unroll
        for (int qi = 0; qi < 4; ++qi) {
            int q = wv * 4 + qi;
            int na = nCnt[q];
            float acc = 0.f;
            int jj = 0;
            for (; jj + 1 < na; jj += 2) {   // 2 gathers in flight
                int p0 = nPack[q][jj], p1 = nPack[q][jj + 1];
                float i0 = nInf[q][jj], i1 = nInf[q][jj + 1];
                float f0 = s_feats[(p0 & 0xFFFFF) * 64 + c];
                float f1 = s_feats[(p1 & 0xFFFFF) * 64 + c];
                float w0 = b2f(cwT[((p0 >> 20) * 64 + c) * CWS + q]);
                float w1 = b2f(cwT[((p1 >> 20) * 64 + c) * CWS + q]);
                acc += i0 * f0 * w0 + i1 * f1 * w1;
            }
            if (jj < na) {
                int p0 = nPack[q][jj];
                float f0 = s_feats[(p0 & 0xFFFFF) * 64 + c];
                float w0 = b2f(cwT[((p0 >> 20) * 64 + c) * CWS + q]);
                acc += nInf[q][jj] * f0 * w0;
            }
            out[(m0 + q) * 64 + c] = acc;
        }
    }
}

extern "C" void kernel_launch(void* const* d_in, const int* in_sizes, int n_in,
                              void* d_out, int out_size, void* d_ws, size_t ws_size,
                              hipStream_t stream) {
    const float* q_pts   = (const float*)d_in[0];
    const float* s_pts   = (const float*)d_in[1];
    const float* s_feats = (const float*)d_in[2];
    const int*   nb      = (const int*)d_in[3];
    const float* kpts    = (const float*)d_in[4];
    const float* W1      = (const float*)d_in[5];
    const float* gamma   = (const float*)d_in[6];
    const float* beta    = (const float*)d_in[7];
    const float* W2      = (const float*)d_in[8];
    const float* b2      = (const float*)d_in[9];
    float* out = (float*)d_out;

    float* ws = (float*)d_ws;
    float* bn = ws;                                        // 128 fp32
    unsigned short* w2b = (unsigned short*)(ws + 128);     // 61440 bf16 (122880 B)
    unsigned short* hst = w2b + 61440;                     // 50000*64 bf16 (6.4 MB)

    hipMemsetAsync(bn, 0, 128 * sizeof(float), stream);
    k_prep<<<STATS_BLOCKS + 30, 256, 0, stream>>>(s_feats, W1, W2, bn, hst, w2b);
    k_main<<<N_PTS / QB, 256, 0, stream>>>(q_pts, s_pts, s_feats, nb, kpts,
                                           gamma, beta, bn, b2, w2b, hst, out);
}